// Round 3
// baseline (1151.773 us; speedup 1.0000x reference)
//
#include <hip/hip_runtime.h>
#include <hip/hip_bf16.h>

typedef __hip_bfloat16 bf16;
typedef __attribute__((ext_vector_type(8))) short s8v;
typedef __attribute__((ext_vector_type(4))) float f32x4;

#define NN 4096
#define FDIM 16
#define BATCH 4
#define TSTEPS 12

static __device__ __forceinline__ short f2bf(float f) {
  bf16 h = __float2bfloat16(f);
  return *reinterpret_cast<short*>(&h);
}

// ---------------- adj (f32) -> bf16 copy ----------------
__global__ __launch_bounds__(256) void adj_to_bf16(const float* __restrict__ adjF,
                                                   short* __restrict__ adjB)
{
  size_t i = ((size_t)blockIdx.x * 256 + threadIdx.x) * 8;
  f32x4 u0 = *(const f32x4*)(adjF + i);
  f32x4 u1 = *(const f32x4*)(adjF + i + 4);
  s8v v;
#pragma unroll
  for (int j = 0; j < 4; j++) { v[j] = f2bf(u0[j]); v[4 + j] = f2bf(u1[j]); }
  *(s8v*)(adjB + i) = v;
}

// ---------------- adjacency GEMM: out[ks][m][col] = adj[m, k0:k0+kc] @ Z[k, col] ----------------
// zt is Z^T: [cols][4096] bf16 (contiguous in k). CONVA: read f32 adj and convert in staging.
template<int BN, bool CONVA>
__global__ __launch_bounds__(256) void gemm_adj(
    const float* __restrict__ adjF,  // [4096][4096] f32   (used if CONVA)
    const short* __restrict__ adjB,  // [4096][4096] bf16  (used if !CONVA)
    const short* __restrict__ zt,    // [cols][4096] bf16 bits
    float* __restrict__ out,         // [gridDim.z][4096][outld]
    int outld, int kChunk)
{
  const int mTile  = blockIdx.x;          // 32 tiles of 128 rows
  const int colBase = blockIdx.y * BN;
  const int ks = blockIdx.z;
  const int k0 = ks * kChunk;

  __shared__ short As[128][72];           // +8 pad: 144B row stride kills bank conflicts
  __shared__ short Bs[BN][72];

  const int tid  = threadIdx.x;
  const int wid  = tid >> 6;
  const int lane = tid & 63;
  const int r16  = lane & 15;
  const int g    = lane >> 4;

  f32x4 acc[2][BN / 16];
#pragma unroll
  for (int i = 0; i < 2; i++)
#pragma unroll
    for (int j = 0; j < BN / 16; j++) acc[i][j] = (f32x4){0.f, 0.f, 0.f, 0.f};

  for (int kt = 0; kt < kChunk; kt += 64) {
    const int kb = k0 + kt;
    // stage A tile: 128x64 bf16
#pragma unroll
    for (int i = 0; i < 4; i++) {
      int c = tid + i * 256;
      int r = c >> 3, cc = (c & 7) << 3;
      if constexpr (CONVA) {
        const float* src = adjF + (size_t)(mTile * 128 + r) * NN + kb + cc;
        f32x4 u0 = *(const f32x4*)src;
        f32x4 u1 = *(const f32x4*)(src + 4);
        s8v v;
#pragma unroll
        for (int j = 0; j < 4; j++) { v[j] = f2bf(u0[j]); v[4 + j] = f2bf(u1[j]); }
        *(s8v*)&As[r][cc] = v;
      } else {
        *(s8v*)&As[r][cc] = *(const s8v*)&adjB[(size_t)(mTile * 128 + r) * NN + kb + cc];
      }
    }
    // stage B tile: BN x 64 (already bf16)
#pragma unroll
    for (int i = 0; i < BN / 32; i++) {
      int c = tid + i * 256;
      int r = c >> 3, cc = (c & 7) << 3;
      *(s8v*)&Bs[r][cc] = *(const s8v*)&zt[(size_t)(colBase + r) * NN + kb + cc];
    }
    __syncthreads();
#pragma unroll
    for (int kk = 0; kk < 64; kk += 32) {
      s8v a0 = *(s8v*)&As[wid * 32 + r16][kk + g * 8];
      s8v a1 = *(s8v*)&As[wid * 32 + 16 + r16][kk + g * 8];
#pragma unroll
      for (int nf = 0; nf < BN / 16; nf++) {
        s8v b = *(s8v*)&Bs[nf * 16 + r16][kk + g * 8];
        acc[0][nf] = __builtin_amdgcn_mfma_f32_16x16x32_bf16(a0, b, acc[0][nf], 0, 0, 0);
        acc[1][nf] = __builtin_amdgcn_mfma_f32_16x16x32_bf16(a1, b, acc[1][nf], 0, 0, 0);
      }
    }
    __syncthreads();
  }
  // C/D layout (verified m89): col = lane&15, row = (lane>>4)*4 + j
#pragma unroll
  for (int mf = 0; mf < 2; mf++)
#pragma unroll
    for (int nf = 0; nf < BN / 16; nf++)
#pragma unroll
      for (int j = 0; j < 4; j++) {
        int row = mTile * 128 + wid * 32 + mf * 16 + g * 4 + j;
        int col = colBase + nf * 16 + r16;
        out[((size_t)ks * NN + row) * outld + col] = acc[mf][nf][j];
      }
}

// ---------------- pack x (f32) into X^T bf16: XT[(b*T+t)*16+f][n] ----------------
__global__ __launch_bounds__(256) void pack_x(const float* __restrict__ x, short* __restrict__ XT)
{
  int idx = blockIdx.x * 256 + threadIdx.x;   // 0..196607 = r*4096+n, r=b*T+t
  int r = idx >> 12, n = idx & 4095;
  const float* xp = x + ((size_t)r * NN + n) * FDIM;
#pragma unroll
  for (int q = 0; q < 4; q++) {
    f32x4 u = *(const f32x4*)(xp + q * 4);
#pragma unroll
    for (int j = 0; j < 4; j++)
      XT[(size_t)(r * 16 + q * 4 + j) * NN + n] = f2bf(u[j]);
  }
}

// ---------------- init h=c=m=1 ----------------
__global__ __launch_bounds__(256) void init_state(float* c_st, float* m_st, short* ztA, short* ztB)
{
  int idx = blockIdx.x * 256 + threadIdx.x;   // 0..262143
  int cc = idx >> 12, n = idx & 4095;
  int b = cc >> 4, f = cc & 15;
  short one = f2bf(1.0f);
  ztA[(size_t)cc * NN + n] = one;                        // h0 rows b*16+f
  ztB[(size_t)(b * 32 + 16 + f) * NN + n] = one;         // m0 slot
  c_st[(size_t)(b * NN + n) * FDIM + f] = 1.0f;
  m_st[(size_t)(b * NN + n) * FDIM + f] = 1.0f;
}

// ---------------- step A: gates + LSTM cell update ----------------
__global__ __launch_bounds__(256) void step_a(
    const float* __restrict__ P,    // [8][4096][64]  (adj@h split-K partials)
    const float* __restrict__ AX,   // [4096][768]    (adj@x, all t)
    const float* __restrict__ Wx, const float* __restrict__ bx,
    const float* __restrict__ Wh, const float* __restrict__ bh,
    float* __restrict__ c_st,
    short* __restrict__ ztB,        // write h_mid into rows b*32+f
    int t)
{
  __shared__ float wx[16][64], wh[16][64], bxs[64], bhs[64];
  int tid = threadIdx.x;
#pragma unroll
  for (int i = 0; i < 4; i++) {
    int c = tid + i * 256;
    wx[c >> 6][c & 63] = Wx[c];
    wh[c >> 6][c & 63] = Wh[c];
  }
  if (tid < 64) { bxs[tid] = bx[tid]; bhs[tid] = bh[tid]; }
  __syncthreads();

  int idx = blockIdx.x * 256 + tid;           // 0..16383 = b*4096+n
  int b = idx >> 12, n = idx & 4095;

  float azx[16], azh[16];
#pragma unroll
  for (int f = 0; f < 16; f++) azx[f] = AX[(size_t)n * 768 + (b * TSTEPS + t) * 16 + f];
#pragma unroll
  for (int f = 0; f < 16; f++) {
    float s = 0.f;
#pragma unroll
    for (int ks = 0; ks < 8; ks++) s += P[(size_t)ks * (NN * 64) + n * 64 + b * 16 + f];
    azh[f] = s;
  }
#pragma unroll
  for (int f = 0; f < 16; f++) {
    float fx = bxs[f], ix = bxs[16 + f], cx = bxs[32 + f], ox = bxs[48 + f];
    float fh = bhs[f], ih = bhs[16 + f], ch = bhs[32 + f], oh = bhs[48 + f];
#pragma unroll
    for (int q = 0; q < 16; q++) {
      fx += azx[q] * wx[q][f];      ix += azx[q] * wx[q][16 + f];
      cx += azx[q] * wx[q][32 + f]; ox += azx[q] * wx[q][48 + f];
      fh += azh[q] * wh[q][f];      ih += azh[q] * wh[q][16 + f];
      ch += azh[q] * wh[q][32 + f]; oh += azh[q] * wh[q][48 + f];
    }
    fx = fmaxf(fx, 0.f); ix = fmaxf(ix, 0.f); cx = fmaxf(cx, 0.f); ox = fmaxf(ox, 0.f);
    fh = fmaxf(fh, 0.f); ih = fmaxf(ih, 0.f); ch = fmaxf(ch, 0.f); oh = fmaxf(oh, 0.f);
    float fg = 1.f / (1.f + __expf(-(fx + fh)));
    float ig = 1.f / (1.f + __expf(-(ix + ih)));
    float og = 1.f / (1.f + __expf(-(ox + oh)));
    float cn = fg * c_st[(size_t)idx * 16 + f] + ig * tanhf(cx + ch);
    float hm = og * tanhf(cn);
    c_st[(size_t)idx * 16 + f] = cn;
    ztB[(size_t)(b * 32 + f) * NN + n] = f2bf(hm);
  }
}

// ---------------- step B: self-attention memory stage ----------------
__global__ __launch_bounds__(256) void step_b(
    const float* __restrict__ P,    // [8][4096][128] (adj@[h_mid|m] partials)
    const float* __restrict__ Wsh, const float* __restrict__ bsh,
    const float* __restrict__ Wsm, const float* __restrict__ bsm,
    float* __restrict__ m_st, float* __restrict__ h_st,
    short* __restrict__ ztA, short* __restrict__ ztB,
    float* __restrict__ outH, int t)
{
  __shared__ float wsh[16][48], wsm[16][48], bshs[48], bsms[48];
  int tid = threadIdx.x;
#pragma unroll
  for (int i = 0; i < 3; i++) {
    int c = tid + i * 256;
    wsh[c / 48][c % 48] = Wsh[c];
    wsm[c / 48][c % 48] = Wsm[c];
  }
  if (tid < 48) { bshs[tid] = bsh[tid]; bsms[tid] = bsm[tid]; }
  __syncthreads();

  int idx = blockIdx.x * 256 + tid;           // b*4096+n
  int b = idx >> 12, n = idx & 4095;

  float ah[16], am[16];
#pragma unroll
  for (int f = 0; f < 16; f++) {
    float s0 = 0.f, s1 = 0.f;
#pragma unroll
    for (int ks = 0; ks < 8; ks++) {
      const float* p = P + (size_t)ks * (NN * 128) + n * 128 + b * 32;
      s0 += p[f];
      s1 += p[16 + f];
    }
    ah[f] = s0; am[f] = s1;
  }
#pragma unroll
  for (int f = 0; f < 16; f++) {
    float ih_ = bshs[f], gh_ = bshs[16 + f], oh_ = bshs[32 + f];
    float im_ = bsms[f], gm_ = bsms[16 + f], om_ = bsms[32 + f];
#pragma unroll
    for (int q = 0; q < 16; q++) {
      ih_ += ah[q] * wsh[q][f];      gh_ += ah[q] * wsh[q][16 + f]; oh_ += ah[q] * wsh[q][32 + f];
      im_ += am[q] * wsm[q][f];      gm_ += am[q] * wsm[q][16 + f]; om_ += am[q] * wsm[q][32 + f];
    }
    ih_ = fmaxf(ih_, 0.f); gh_ = fmaxf(gh_, 0.f); oh_ = fmaxf(oh_, 0.f);
    im_ = fmaxf(im_, 0.f); gm_ = fmaxf(gm_, 0.f); om_ = fmaxf(om_, 0.f);
    float i2 = 1.f / (1.f + __expf(-(ih_ + im_)));
    float g2 = 1.f / (1.f + __expf(-(gh_ + gm_)));
    float o2 = 1.f / (1.f + __expf(-(oh_ + om_)));
    float mo = m_st[(size_t)idx * 16 + f];
    float mn = i2 * mo + (1.f - i2) * g2;
    float hn = mn * o2;
    m_st[(size_t)idx * 16 + f] = mn;
    h_st[(size_t)idx * 16 + f] = hn;
    ztA[(size_t)(b * 16 + f) * NN + n] = f2bf(hn);
    ztB[(size_t)(b * 32 + 16 + f) * NN + n] = f2bf(mn);
    outH[((size_t)(b * TSTEPS + t) * NN + n) * FDIM + f] = hn;
  }
}

// ---------------- final: last_h, last_c, last_m (f32 out) ----------------
__global__ __launch_bounds__(256) void finalize(
    const float* __restrict__ h_st, const float* __restrict__ c_st,
    const float* __restrict__ m_st, float* __restrict__ out)
{
  int idx = blockIdx.x * 256 + threadIdx.x;   // 0..262143
  size_t base = (size_t)BATCH * TSTEPS * NN * FDIM;
  out[base + idx]          = h_st[idx];
  out[base + 262144 + idx] = c_st[idx];
  out[base + 524288 + idx] = m_st[idx];
}

extern "C" void kernel_launch(void* const* d_in, const int* in_sizes, int n_in,
                              void* d_out, int out_size, void* d_ws, size_t ws_size,
                              hipStream_t stream)
{
  const float* x    = (const float*)d_in[0];
  const float* adjF = (const float*)d_in[1];
  const float* Wx   = (const float*)d_in[2];
  const float* bx   = (const float*)d_in[3];
  const float* Wh   = (const float*)d_in[4];
  const float* bh   = (const float*)d_in[5];
  const float* Wsh  = (const float*)d_in[6];
  const float* bsh  = (const float*)d_in[7];
  const float* Wsm  = (const float*)d_in[8];
  const float* bsm  = (const float*)d_in[9];
  float* out = (float*)d_out;

  char* ws = (char*)d_ws;
  float* AX   = (float*)ws;                    // 4096*768*4   = 12,582,912
  float* P    = (float*)(ws + 12582912);       // 8*4096*128*4 = 16,777,216
  short* XT   = (short*)(ws + 29360128);       // 768*4096*2   =  6,291,456
  short* ztA  = (short*)(ws + 35651584);       // 64*4096*2    =    524,288
  short* ztB  = (short*)(ws + 36175872);       // 128*4096*2   =  1,048,576
  float* c_st = (float*)(ws + 37224448);       // 1,048,576 each
  float* m_st = (float*)(ws + 38273024);
  float* h_st = (float*)(ws + 39321600);
  short* adjB = (short*)(ws + 40370176);       // 4096*4096*2  = 33,554,432 (tier-full only)
  const bool full = ws_size >= (size_t)73924608;

  init_state<<<1024, 256, 0, stream>>>(c_st, m_st, ztA, ztB);
  pack_x<<<768, 256, 0, stream>>>(x, XT);
  if (full) adj_to_bf16<<<8192, 256, 0, stream>>>(adjF, adjB);

  // adj @ x for all (b,t): [4096,4096] x [4096,768] -> AX
  if (full) gemm_adj<64, false><<<dim3(32, 12, 1), 256, 0, stream>>>(adjF, adjB, XT, AX, 768, 4096);
  else      gemm_adj<64, true ><<<dim3(32, 12, 1), 256, 0, stream>>>(adjF, adjB, XT, AX, 768, 4096);

  for (int t = 0; t < TSTEPS; t++) {
    // adj @ h : 64 cols, split-K=8
    if (full) gemm_adj<64, false><<<dim3(32, 1, 8), 256, 0, stream>>>(adjF, adjB, ztA, P, 64, 512);
    else      gemm_adj<64, true ><<<dim3(32, 1, 8), 256, 0, stream>>>(adjF, adjB, ztA, P, 64, 512);
    step_a<<<64, 256, 0, stream>>>(P, AX, Wx, bx, Wh, bh, c_st, ztB, t);
    // adj @ [h_mid | m] : 128 cols, split-K=8
    if (full) gemm_adj<128, false><<<dim3(32, 1, 8), 256, 0, stream>>>(adjF, adjB, ztB, P, 128, 512);
    else      gemm_adj<128, true ><<<dim3(32, 1, 8), 256, 0, stream>>>(adjF, adjB, ztB, P, 128, 512);
    step_b<<<64, 256, 0, stream>>>(P, Wsh, bsh, Wsm, bsm, m_st, h_st, ztA, ztB, out, t);
  }
  finalize<<<1024, 256, 0, stream>>>(h_st, c_st, m_st, out);
}